// Round 5
// baseline (151.387 us; speedup 1.0000x reference)
//
#include <hip/hip_runtime.h>
#include <stdint.h>

#define B_ROWS 4096
#define C_OUT  2048
#define C_IN   2048
#define EPS    1e-5f

typedef __attribute__((ext_vector_type(8))) short bf16x8;  // 8 bf16 = 4 VGPRs
typedef __attribute__((ext_vector_type(4))) float f32x4;

// RNE f32 -> bf16
__device__ __forceinline__ unsigned short f2bf(float f) {
    uint32_t u = __float_as_uint(f);
    uint32_t r = (u + 0x7fffu + ((u >> 16) & 1u)) >> 16;
    return (unsigned short)r;
}

// One launch converts both x and w (f32 -> bf16, float4-granular)
__global__ void cvt_f32_bf16_kernel(const float* __restrict__ x,
                                    const float* __restrict__ w,
                                    unsigned short* __restrict__ xb,
                                    unsigned short* __restrict__ wb,
                                    int nx4, int nw4) {
    int i = blockIdx.x * blockDim.x + threadIdx.x;
    const float* src;
    unsigned short* dst;
    if (i < nx4) {
        src = x; dst = xb;
    } else {
        i -= nx4;
        if (i >= nw4) return;
        src = w; dst = wb;
    }
    float4 v = ((const float4*)src)[i];
    ushort4 o;
    o.x = f2bf(v.x); o.y = f2bf(v.y); o.z = f2bf(v.z); o.w = f2bf(v.w);
    ((ushort4*)dst)[i] = o;
}

// Fused bf16 GEMM (C = A @ W^T + bias) + GroupNorm(32 groups of 64) + hardtanh.
// Tile 128 rows x 64 cols, BK=64, 4 waves = (row-half wr) x (K-half kh), each
// wave a 64x64 tile over half the K slab. DOUBLE-BUFFERED LDS (2 x 24 KB),
// ONE barrier per K-iter: loads for iter k+1 issue right after barrier k and
// are drained at barrier k+1 -> a full compute phase hides the L2 latency
// (R4 exposed it raw: 8% true MFMA duty). K-half pairs combine via LDS in
// lane-contiguous f32x4 layout (2-way = free, was 8-way in R4). Swizzled
// staging: (row,q) at q^(row&7), conflict-free frag reads.
__global__ __launch_bounds__(256, 3)
void gemm_gn_kernel(const unsigned short* __restrict__ A,  // [4096][2048] bf16
                    const unsigned short* __restrict__ W,  // [2048][2048] bf16
                    const float* __restrict__ bias,
                    const float* __restrict__ gnw,
                    const float* __restrict__ gnb,
                    float* __restrict__ out) {
    // buffer b: A at smem + b*12288 (8192 shorts), B at +8192 (4096 shorts)
    __shared__ __align__(16) unsigned short smem[2 * 12288];  // 48 KB

    // L2-locality swizzle: contiguous 512-block cohorts cover all 32 br x a
    // 16-wide bc slice (B slice ~4.2 MB stays hot in L2s).
    const int flat = blockIdx.x;
    const int br   = (flat >> 4) & 31;
    const int bc   = (flat & 15) | ((flat >> 9) << 4);
    const int t    = threadIdx.x;     // 0..255
    const int lane = t & 63;
    const int wave = t >> 6;          // 0..3
    const int wr   = wave & 1;        // row half (rows wr*64..+64)
    const int kh   = wave >> 1;       // K half (k offset kh*32 within BK=64)
    const int c16  = lane & 15;
    const int quad = lane >> 4;

    f32x4 acc[4][4];
#pragma unroll
    for (int i = 0; i < 4; i++)
#pragma unroll
        for (int j = 0; j < 4; j++) acc[i][j] = (f32x4){0.f, 0.f, 0.f, 0.f};

    // ---- staging addresses ----
    // issue n: granule G = n*256+t; row = G>>3 = n*32+(t>>3); phys q' = t&7;
    // holds global q = (t&7)^(row&7) = (t&7)^((t>>3)&7)  (n*32 == 0 mod 8).
    const int r0 = t >> 3;                          // 0..31
    const int qo = ((t & 7) ^ (r0 & 7)) * 8;        // element offset in row
    const unsigned short* gA = A + (size_t)(br * 128 + r0) * C_IN + qo;
    const unsigned short* gB = W + (size_t)(bc * 64 + r0) * C_IN + qo;

    // fragment read: logical granule q = kh*4+quad lives at q ^ (c16&7)
    const int qs = (((kh << 2) | quad) ^ (c16 & 7)) * 8;

#define STAGE(buf, k0)                                                                     \
    do {                                                                                   \
        unsigned short* sa = smem + (buf) * 12288;                                         \
        unsigned short* sb = sa + 8192;                                                    \
        _Pragma("unroll")                                                                  \
        for (int n = 0; n < 4; n++)                                                        \
            __builtin_amdgcn_global_load_lds(                                              \
                (const __attribute__((address_space(1))) void*)(gA + (size_t)(n * 32) * C_IN + (k0)), \
                (__attribute__((address_space(3))) void*)(sa + n * 2048 + t * 8), 16, 0, 0); \
        _Pragma("unroll")                                                                  \
        for (int n = 0; n < 2; n++)                                                        \
            __builtin_amdgcn_global_load_lds(                                              \
                (const __attribute__((address_space(1))) void*)(gB + (size_t)(n * 32) * C_IN + (k0)), \
                (__attribute__((address_space(3))) void*)(sb + n * 2048 + t * 8), 16, 0, 0); \
    } while (0)

    STAGE(0, 0);
    int cur = 0;
    for (int it = 0; it < 32; ++it) {
        __syncthreads();   // drains buf[cur] loads; all waves done reading buf[cur^1]
        if (it < 31) STAGE(cur ^ 1, (it + 1) * 64);

        const unsigned short* sa = smem + cur * 12288;
        const unsigned short* sb = sa + 8192;
        bf16x8 a[4], b[4];
#pragma unroll
        for (int i = 0; i < 4; i++)
            a[i] = *(const bf16x8*)(sa + (wr * 64 + i * 16 + c16) * 64 + qs);
#pragma unroll
        for (int j = 0; j < 4; j++)
            b[j] = *(const bf16x8*)(sb + (j * 16 + c16) * 64 + qs);
#pragma unroll
        for (int i = 0; i < 4; i++)
#pragma unroll
            for (int j = 0; j < 4; j++)
                acc[i][j] = __builtin_amdgcn_mfma_f32_16x16x32_bf16(a[i], b[j], acc[i][j], 0, 0, 0);
        cur ^= 1;
    }

    // ---- combine K-halves via LDS (single phase, 32 KB of the 48 KB) ----
    // lane-contiguous layout: each (i,j) is 64 lanes x 16 B = 1 KB contiguous
    // -> 2 lanes/bank = free. Writer/reader use identical (lane,i,j) indexing.
    __syncthreads();   // all MFMA reads of smem complete
    float* fbuf = (float*)smem;
    if (kh == 1) {
#pragma unroll
        for (int i = 0; i < 4; i++)
#pragma unroll
            for (int j = 0; j < 4; j++)
                *(f32x4*)(fbuf + wr * 4096 + i * 1024 + j * 256 + lane * 4) = acc[i][j];
    }
    __syncthreads();
    if (kh == 1) return;   // no further barriers below
#pragma unroll
    for (int i = 0; i < 4; i++)
#pragma unroll
        for (int j = 0; j < 4; j++)
            acc[i][j] += *(const f32x4*)(fbuf + wr * 4096 + i * 1024 + j * 256 + lane * 4);

    // ---- epilogue: bias + GroupNorm + hardtanh (waves 0,1 only) ----
    // acc[i][j][r]: row = br*128 + wr*64 + i*16 + quad*4 + r,
    //               col = bc*64 + j*16 + c16. Wave's 64 cols = one group.
    const int colbase = bc * 64;
    const int rowbase = br * 128 + wr * 64;
    float bv[4], gw[4], gb[4];
#pragma unroll
    for (int j = 0; j < 4; j++) {
        int col = colbase + j * 16 + c16;
        bv[j] = bias[col];
        gw[j] = gnw[col];
        gb[j] = gnb[col];
    }
#pragma unroll
    for (int i = 0; i < 4; i++) {
#pragma unroll
        for (int r = 0; r < 4; r++) {
            float s = 0.f, ss = 0.f;
#pragma unroll
            for (int j = 0; j < 4; j++) {
                float v = acc[i][j][r] + bv[j];
                acc[i][j][r] = v;
                s += v;
                ss += v * v;
            }
#pragma unroll
            for (int m = 1; m < 16; m <<= 1) {
                s  += __shfl_xor(s, m, 64);
                ss += __shfl_xor(ss, m, 64);
            }
            float mean = s * (1.f / 64.f);
            float var  = ss * (1.f / 64.f) - mean * mean;
            float rstd = rsqrtf(var + EPS);
            int row = rowbase + i * 16 + quad * 4 + r;
            float* orow = out + (size_t)row * C_OUT;
#pragma unroll
            for (int j = 0; j < 4; j++) {
                float v = (acc[i][j][r] - mean) * rstd * gw[j] + gb[j];
                v = fminf(1.f, fmaxf(-1.f, v));
                orow[colbase + j * 16 + c16] = v;
            }
        }
    }
}

extern "C" void kernel_launch(void* const* d_in, const int* in_sizes, int n_in,
                              void* d_out, int out_size, void* d_ws, size_t ws_size,
                              hipStream_t stream) {
    const float* x    = (const float*)d_in[0];   // [4096, 2048]
    const float* w    = (const float*)d_in[1];   // [2048, 2048]
    const float* bias = (const float*)d_in[2];   // [2048]
    const float* gnw  = (const float*)d_in[3];   // [2048]
    const float* gnb  = (const float*)d_in[4];   // [2048]
    float* out = (float*)d_out;

    unsigned short* xb = (unsigned short*)d_ws;                        // 16 MB
    unsigned short* wb = xb + (size_t)B_ROWS * C_IN;                   //  8 MB

    const int nx4 = B_ROWS * C_IN / 4;   // 2097152
    const int nw4 = C_OUT * C_IN / 4;    // 1048576
    cvt_f32_bf16_kernel<<<(nx4 + nw4 + 255) / 256, 256, 0, stream>>>(x, w, xb, wb, nx4, nw4);

    gemm_gn_kernel<<<1024, 256, 0, stream>>>(xb, wb, bias, gnw, gnb, out);
}

// Round 6
// 137.227 us; speedup vs baseline: 1.1032x; 1.1032x over previous
//
#include <hip/hip_runtime.h>
#include <stdint.h>

#define B_ROWS 4096
#define C_OUT  2048
#define C_IN   2048
#define EPS    1e-5f

typedef __attribute__((ext_vector_type(8))) short bf16x8;  // 8 bf16 = 4 VGPRs
typedef __attribute__((ext_vector_type(4))) float f32x4;

// RNE f32 -> bf16
__device__ __forceinline__ unsigned short f2bf(float f) {
    uint32_t u = __float_as_uint(f);
    uint32_t r = (u + 0x7fffu + ((u >> 16) & 1u)) >> 16;
    return (unsigned short)r;
}

// One launch converts both x and w (f32 -> bf16, float4-granular)
__global__ void cvt_f32_bf16_kernel(const float* __restrict__ x,
                                    const float* __restrict__ w,
                                    unsigned short* __restrict__ xb,
                                    unsigned short* __restrict__ wb,
                                    int nx4, int nw4) {
    int i = blockIdx.x * blockDim.x + threadIdx.x;
    const float* src;
    unsigned short* dst;
    if (i < nx4) {
        src = x; dst = xb;
    } else {
        i -= nx4;
        if (i >= nw4) return;
        src = w; dst = wb;
    }
    float4 v = ((const float4*)src)[i];
    ushort4 o;
    o.x = f2bf(v.x); o.y = f2bf(v.y); o.z = f2bf(v.z); o.w = f2bf(v.w);
    ((ushort4*)dst)[i] = o;
}

// Fused bf16 GEMM (C = A @ W^T + bias) + GroupNorm(32 groups of 64) + hardtanh.
// Tile 128x128 (max reuse: 512 MB total L2->LDS traffic, lowest of any config),
// 4 waves in 2x2, each 64x64 (wave's 64 cols == one GN group -> in-wave shuffle
// GN, no extra pass). BK=64: 32 MFMA per wave per barrier. Double-buffered LDS
// (2 x 32 KB = 64 KB), ONE barrier per K-iter: stage(k+1) issues right after
// barrier k, drains at barrier k+1 behind a full compute phase (~700 cyc/SIMD
// shadow >> L2 latency). Residency EXACT: 64 KB -> 2 blocks/CU, grid 512 =
// 2/CU, no straggler tail (R5's mistake). Natural dispatch order (R5's swizzle
// raised FETCH 70->112 MB). Swizzle (8 granules/row): (row,q) at q^(row&7) --
// staging offset issue-invariant, frag reads 2 lanes/granule = conflict-free
// (R4-verified: 0 conflicts).
__global__ __launch_bounds__(256, 2)
void gemm_gn_kernel(const unsigned short* __restrict__ A,  // [4096][2048] bf16
                    const unsigned short* __restrict__ W,  // [2048][2048] bf16
                    const float* __restrict__ bias,
                    const float* __restrict__ gnw,
                    const float* __restrict__ gnb,
                    float* __restrict__ out) {
    // buffer b at smem + b*16384: A tile (8192 shorts) then B tile (8192)
    __shared__ __align__(16) unsigned short smem[2 * 16384];  // 64 KB

    const int bc   = blockIdx.x;      // 0..15 col block (128 cols)
    const int br   = blockIdx.y;      // 0..31 row block (128 rows)
    const int t    = threadIdx.x;     // 0..255
    const int lane = t & 63;
    const int wave = t >> 6;          // 0..3
    const int wr   = wave >> 1;       // row half
    const int wc   = wave & 1;        // col half
    const int c16  = lane & 15;
    const int quad = lane >> 4;

    f32x4 acc[4][4];
#pragma unroll
    for (int i = 0; i < 4; i++)
#pragma unroll
        for (int j = 0; j < 4; j++) acc[i][j] = (f32x4){0.f, 0.f, 0.f, 0.f};

    // ---- staging addresses ----
    // issue n (granule G = n*256+t): row = n*32 + (t>>3), phys q' = t&7,
    // global q = (t&7)^(row&7) = (t&7)^((t>>3)&7)  (n*32 == 0 mod 8).
    const int r0 = t >> 3;                          // 0..31
    const int qo = ((t & 7) ^ (r0 & 7)) * 8;        // element offset in row
    const unsigned short* gA = A + (size_t)(br * 128 + r0) * C_IN + qo;
    const unsigned short* gB = W + (size_t)(bc * 128 + r0) * C_IN + qo;

#define STAGE(buf, k0)                                                                     \
    do {                                                                                   \
        unsigned short* sa = smem + (buf) * 16384;                                         \
        unsigned short* sb = sa + 8192;                                                    \
        _Pragma("unroll")                                                                  \
        for (int n = 0; n < 4; n++)                                                        \
            __builtin_amdgcn_global_load_lds(                                              \
                (const __attribute__((address_space(1))) void*)(gA + (size_t)(n * 32) * C_IN + (k0)), \
                (__attribute__((address_space(3))) void*)(sa + n * 2048 + t * 8), 16, 0, 0); \
        _Pragma("unroll")                                                                  \
        for (int n = 0; n < 4; n++)                                                        \
            __builtin_amdgcn_global_load_lds(                                              \
                (const __attribute__((address_space(1))) void*)(gB + (size_t)(n * 32) * C_IN + (k0)), \
                (__attribute__((address_space(3))) void*)(sb + n * 2048 + t * 8), 16, 0, 0); \
    } while (0)

    STAGE(0, 0);
    int cur = 0;
    for (int it = 0; it < 32; ++it) {
        __syncthreads();   // drains buf[cur] staging; all waves done with buf[cur^1]
        if (it < 31) STAGE(cur ^ 1, (it + 1) * 64);

        const unsigned short* sa = smem + cur * 16384;
        const unsigned short* sb = sa + 8192;
#pragma unroll
        for (int sub = 0; sub < 2; sub++) {
            // logical granule q = sub*4+quad lives at phys q ^ (c16&7)
            const int qs = (((sub << 2) | quad) ^ (c16 & 7)) * 8;
            bf16x8 a[4], b[4];
#pragma unroll
            for (int i = 0; i < 4; i++)
                a[i] = *(const bf16x8*)(sa + (wr * 64 + i * 16 + c16) * 64 + qs);
#pragma unroll
            for (int j = 0; j < 4; j++)
                b[j] = *(const bf16x8*)(sb + (wc * 64 + j * 16 + c16) * 64 + qs);
#pragma unroll
            for (int i = 0; i < 4; i++)
#pragma unroll
                for (int j = 0; j < 4; j++)
                    acc[i][j] = __builtin_amdgcn_mfma_f32_16x16x32_bf16(a[i], b[j], acc[i][j], 0, 0, 0);
        }
        cur ^= 1;
    }

    // ---- epilogue: bias + GroupNorm + hardtanh ----
    // acc[i][j][r]: row = br*128 + wr*64 + i*16 + quad*4 + r,
    //               col = bc*128 + wc*64 + j*16 + c16. Wave's 64 cols = 1 group.
    const int colbase = bc * 128 + wc * 64;
    const int rowbase = br * 128 + wr * 64;
    float bv[4], gw[4], gb[4];
#pragma unroll
    for (int j = 0; j < 4; j++) {
        int col = colbase + j * 16 + c16;
        bv[j] = bias[col];
        gw[j] = gnw[col];
        gb[j] = gnb[col];
    }
#pragma unroll
    for (int i = 0; i < 4; i++) {
#pragma unroll
        for (int r = 0; r < 4; r++) {
            float s = 0.f, ss = 0.f;
#pragma unroll
            for (int j = 0; j < 4; j++) {
                float v = acc[i][j][r] + bv[j];
                acc[i][j][r] = v;
                s += v;
                ss += v * v;
            }
#pragma unroll
            for (int m = 1; m < 16; m <<= 1) {
                s  += __shfl_xor(s, m, 64);
                ss += __shfl_xor(ss, m, 64);
            }
            float mean = s * (1.f / 64.f);
            float var  = ss * (1.f / 64.f) - mean * mean;
            float rstd = rsqrtf(var + EPS);
            int row = rowbase + i * 16 + quad * 4 + r;
            float* orow = out + (size_t)row * C_OUT;
#pragma unroll
            for (int j = 0; j < 4; j++) {
                float v = (acc[i][j][r] - mean) * rstd * gw[j] + gb[j];
                v = fminf(1.f, fmaxf(-1.f, v));
                orow[colbase + j * 16 + c16] = v;
            }
        }
    }
}

extern "C" void kernel_launch(void* const* d_in, const int* in_sizes, int n_in,
                              void* d_out, int out_size, void* d_ws, size_t ws_size,
                              hipStream_t stream) {
    const float* x    = (const float*)d_in[0];   // [4096, 2048]
    const float* w    = (const float*)d_in[1];   // [2048, 2048]
    const float* bias = (const float*)d_in[2];   // [2048]
    const float* gnw  = (const float*)d_in[3];   // [2048]
    const float* gnb  = (const float*)d_in[4];   // [2048]
    float* out = (float*)d_out;

    unsigned short* xb = (unsigned short*)d_ws;                        // 16 MB
    unsigned short* wb = xb + (size_t)B_ROWS * C_IN;                   //  8 MB

    const int nx4 = B_ROWS * C_IN / 4;   // 2097152
    const int nw4 = C_OUT * C_IN / 4;    // 1048576
    cvt_f32_bf16_kernel<<<(nx4 + nw4 + 255) / 256, 256, 0, stream>>>(x, w, xb, wb, nx4, nw4);

    dim3 grid(C_OUT / 128, B_ROWS / 128);  // (16, 32) = 512 blocks = exactly 2/CU
    gemm_gn_kernel<<<grid, 256, 0, stream>>>(xb, wb, bias, gnw, gnb, out);
}

// Round 7
// 136.653 us; speedup vs baseline: 1.1078x; 1.0042x over previous
//
#include <hip/hip_runtime.h>
#include <stdint.h>

#define B_ROWS 4096
#define C_OUT  2048
#define C_IN   2048
#define EPS    1e-5f

typedef __attribute__((ext_vector_type(8))) short bf16x8;  // 8 bf16 = 4 VGPRs
typedef __attribute__((ext_vector_type(4))) float f32x4;

// RNE f32 -> bf16
__device__ __forceinline__ unsigned short f2bf(float f) {
    uint32_t u = __float_as_uint(f);
    uint32_t r = (u + 0x7fffu + ((u >> 16) & 1u)) >> 16;
    return (unsigned short)r;
}

// One launch converts both x and w (f32 -> bf16, float4-granular)
__global__ void cvt_f32_bf16_kernel(const float* __restrict__ x,
                                    const float* __restrict__ w,
                                    unsigned short* __restrict__ xb,
                                    unsigned short* __restrict__ wb,
                                    int nx4, int nw4) {
    int i = blockIdx.x * blockDim.x + threadIdx.x;
    const float* src;
    unsigned short* dst;
    if (i < nx4) {
        src = x; dst = xb;
    } else {
        i -= nx4;
        if (i >= nw4) return;
        src = w; dst = wb;
    }
    float4 v = ((const float4*)src)[i];
    ushort4 o;
    o.x = f2bf(v.x); o.y = f2bf(v.y); o.z = f2bf(v.z); o.w = f2bf(v.w);
    ((ushort4*)dst)[i] = o;
}

// Fused bf16 GEMM (C = A @ W^T + bias) + GroupNorm(32 groups of 64) + hardtanh.
// R6 (dbuf, 128x128 tile, exact 2 blocks/CU) + R4 (split-K waves) merged:
// 512-thread blocks, 8 waves = (row-half wr) x (col-half wc) x (K-half kh),
// each wave a 64x64 tile over half of each BK=64 slab. Same LDS (2x32 KB) and
// block count (512 = exactly 2/CU, no tail) as R6, but 16 waves/CU = 4/SIMD
// -> 4 independent streams cover the staging drain that left R6 at 2x its
// structural floor (102k cyc vs ~50k: LDS reads 37-49k || L2 staging 37k).
// Single barrier per K-iter (stage k+1 right after barrier k, drains at k+1).
// K-half combine in R5's lane-contiguous conflict-free layout (64 KB = smem).
// Swizzle (8 granules/row): (row,q) at q^(row&7); staging offset
// issue-invariant; frag reads 2 lanes/granule = free (R4/R6: 0 conflicts).
__global__ __launch_bounds__(512, 4)
void gemm_gn_kernel(const unsigned short* __restrict__ A,  // [4096][2048] bf16
                    const unsigned short* __restrict__ W,  // [2048][2048] bf16
                    const float* __restrict__ bias,
                    const float* __restrict__ gnw,
                    const float* __restrict__ gnb,
                    float* __restrict__ out) {
    // buffer b at smem + b*16384: A tile (8192 shorts) then B tile (8192)
    __shared__ __align__(16) unsigned short smem[2 * 16384];  // 64 KB

    const int bc   = blockIdx.x;      // 0..15 col block (128 cols)
    const int br   = blockIdx.y;      // 0..31 row block (128 rows)
    const int t    = threadIdx.x;     // 0..511
    const int lane = t & 63;
    const int wave = t >> 6;          // 0..7
    const int wr   = wave & 1;        // row half
    const int wc   = (wave >> 1) & 1; // col half
    const int kh   = wave >> 2;       // K half (k offset kh*32 within BK=64)
    const int c16  = lane & 15;
    const int quad = lane >> 4;

    f32x4 acc[4][4];
#pragma unroll
    for (int i = 0; i < 4; i++)
#pragma unroll
        for (int j = 0; j < 4; j++) acc[i][j] = (f32x4){0.f, 0.f, 0.f, 0.f};

    // ---- staging addresses (512 threads: 2 issues for A, 2 for B) ----
    // issue n (granule G = n*512+t): row = n*64 + (t>>3), phys q' = t&7,
    // global q = (t&7)^(row&7) = (t&7)^((t>>3)&7)  (n*64 == 0 mod 8).
    const int r0 = t >> 3;                          // 0..63
    const int qo = ((t & 7) ^ (r0 & 7)) * 8;        // element offset in row
    const unsigned short* gA = A + (size_t)(br * 128 + r0) * C_IN + qo;
    const unsigned short* gB = W + (size_t)(bc * 128 + r0) * C_IN + qo;

#define STAGE(buf, k0)                                                                     \
    do {                                                                                   \
        unsigned short* sa = smem + (buf) * 16384;                                         \
        unsigned short* sb = sa + 8192;                                                    \
        _Pragma("unroll")                                                                  \
        for (int n = 0; n < 2; n++)                                                        \
            __builtin_amdgcn_global_load_lds(                                              \
                (const __attribute__((address_space(1))) void*)(gA + (size_t)(n * 64) * C_IN + (k0)), \
                (__attribute__((address_space(3))) void*)(sa + n * 4096 + t * 8), 16, 0, 0); \
        _Pragma("unroll")                                                                  \
        for (int n = 0; n < 2; n++)                                                        \
            __builtin_amdgcn_global_load_lds(                                              \
                (const __attribute__((address_space(1))) void*)(gB + (size_t)(n * 64) * C_IN + (k0)), \
                (__attribute__((address_space(3))) void*)(sb + n * 4096 + t * 8), 16, 0, 0); \
    } while (0)

    // fragment read: logical granule q = kh*4+quad lives at phys q ^ (c16&7)
    const int qs = (((kh << 2) | quad) ^ (c16 & 7)) * 8;

    STAGE(0, 0);
    int cur = 0;
    for (int it = 0; it < 32; ++it) {
        __syncthreads();   // drains buf[cur] staging; all waves done with buf[cur^1]
        if (it < 31) STAGE(cur ^ 1, (it + 1) * 64);

        const unsigned short* sa = smem + cur * 16384;
        const unsigned short* sb = sa + 8192;
        bf16x8 a[4], b[4];
#pragma unroll
        for (int i = 0; i < 4; i++)
            a[i] = *(const bf16x8*)(sa + (wr * 64 + i * 16 + c16) * 64 + qs);
#pragma unroll
        for (int j = 0; j < 4; j++)
            b[j] = *(const bf16x8*)(sb + (wc * 64 + j * 16 + c16) * 64 + qs);
#pragma unroll
        for (int i = 0; i < 4; i++)
#pragma unroll
            for (int j = 0; j < 4; j++)
                acc[i][j] = __builtin_amdgcn_mfma_f32_16x16x32_bf16(a[i], b[j], acc[i][j], 0, 0, 0);
        cur ^= 1;
    }

    // ---- combine K-halves via LDS (64 KB, exactly smem) ----
    // lane-contiguous layout: each (wave&3, i, j) slab is 64 lanes x 16 B = 1 KB
    // contiguous -> 2 lanes/bank = free (R5-verified 0 conflicts).
    __syncthreads();   // all MFMA reads of smem complete
    float* fbuf = (float*)smem;
    if (kh == 1) {
#pragma unroll
        for (int i = 0; i < 4; i++)
#pragma unroll
            for (int j = 0; j < 4; j++)
                *(f32x4*)(fbuf + (wave & 3) * 4096 + i * 1024 + j * 256 + lane * 4) = acc[i][j];
    }
    __syncthreads();
    if (kh == 1) return;   // no further barriers below
#pragma unroll
    for (int i = 0; i < 4; i++)
#pragma unroll
        for (int j = 0; j < 4; j++)
            acc[i][j] += *(const f32x4*)(fbuf + (wave & 3) * 4096 + i * 1024 + j * 256 + lane * 4);

    // ---- epilogue: bias + GroupNorm + hardtanh (kh==0 waves) ----
    // acc[i][j][r]: row = br*128 + wr*64 + i*16 + quad*4 + r,
    //               col = bc*128 + wc*64 + j*16 + c16. Wave's 64 cols = 1 group.
    const int colbase = bc * 128 + wc * 64;
    const int rowbase = br * 128 + wr * 64;
    float bv[4], gw[4], gb[4];
#pragma unroll
    for (int j = 0; j < 4; j++) {
        int col = colbase + j * 16 + c16;
        bv[j] = bias[col];
        gw[j] = gnw[col];
        gb[j] = gnb[col];
    }
#pragma unroll
    for (int i = 0; i < 4; i++) {
#pragma unroll
        for (int r = 0; r < 4; r++) {
            float s = 0.f, ss = 0.f;
#pragma unroll
            for (int j = 0; j < 4; j++) {
                float v = acc[i][j][r] + bv[j];
                acc[i][j][r] = v;
                s += v;
                ss += v * v;
            }
#pragma unroll
            for (int m = 1; m < 16; m <<= 1) {
                s  += __shfl_xor(s, m, 64);
                ss += __shfl_xor(ss, m, 64);
            }
            float mean = s * (1.f / 64.f);
            float var  = ss * (1.f / 64.f) - mean * mean;
            float rstd = rsqrtf(var + EPS);
            int row = rowbase + i * 16 + quad * 4 + r;
            float* orow = out + (size_t)row * C_OUT;
#pragma unroll
            for (int j = 0; j < 4; j++) {
                float v = (acc[i][j][r] - mean) * rstd * gw[j] + gb[j];
                v = fminf(1.f, fmaxf(-1.f, v));
                orow[colbase + j * 16 + c16] = v;
            }
        }
    }
}

extern "C" void kernel_launch(void* const* d_in, const int* in_sizes, int n_in,
                              void* d_out, int out_size, void* d_ws, size_t ws_size,
                              hipStream_t stream) {
    const float* x    = (const float*)d_in[0];   // [4096, 2048]
    const float* w    = (const float*)d_in[1];   // [2048, 2048]
    const float* bias = (const float*)d_in[2];   // [2048]
    const float* gnw  = (const float*)d_in[3];   // [2048]
    const float* gnb  = (const float*)d_in[4];   // [2048]
    float* out = (float*)d_out;

    unsigned short* xb = (unsigned short*)d_ws;                        // 16 MB
    unsigned short* wb = xb + (size_t)B_ROWS * C_IN;                   //  8 MB

    const int nx4 = B_ROWS * C_IN / 4;   // 2097152
    const int nw4 = C_OUT * C_IN / 4;    // 1048576
    cvt_f32_bf16_kernel<<<(nx4 + nw4 + 255) / 256, 256, 0, stream>>>(x, w, xb, wb, nx4, nw4);

    dim3 grid(C_OUT / 128, B_ROWS / 128);  // (16, 32) = 512 blocks = exactly 2/CU
    gemm_gn_kernel<<<grid, 512, 0, stream>>>(xb, wb, bias, gnw, gnb, out);
}